// Round 16
// baseline (12.650 us; speedup 1.0000x reference)
//
#include <hip/hip_runtime.h>

#define N_ 8
#define C_ 64
#define L_ 512
#define KST 68        // k2b row stride (dwords): ==4 mod 32 -> uniform-8 b128 (floor)
#define XCST 104      // xc/a16 row stride (f16): 52 dwords ==20 mod 32 -> 2-way b128
#define XB2 72        // xbs inner row stride (f16): 144B, 16B-multiple
#define XBSUB (20 * XB2)  // one jj-mod-4 subarray: 20 rows

#define C2F 2.8853900817779268f   // 2*log2(e)

typedef _Float16 f16x8 __attribute__((ext_vector_type(8)));
typedef _Float16 f16x4 __attribute__((ext_vector_type(4)));
typedef float    f32x4 __attribute__((ext_vector_type(4)));

__device__ __forceinline__ float rcp_f(float x) { return __builtin_amdgcn_rcpf(x); }
__device__ __forceinline__ float ex2(float x)   { return __builtin_amdgcn_exp2f(x); }
__device__ __forceinline__ float rdlane(float v, int l) {
  return __builtin_bit_cast(float, __builtin_amdgcn_readlane(__builtin_bit_cast(int, v), l));
}

// Single fused kernel; proj AND AV on the matrix pipe.
// k2b stores E = exp2(C2F * proj): sigma = rcp(fma(Ek, Eq, 1)) -> no exp in loop.
// Eq row broadcast via v_readlane (1 ds_read_b32/wave instead of 16 b128).
// grid 512 = (n = bx&7 -> XCD-local batch, t = bx>>3), 512 thr = 8 waves.
__global__ __launch_bounds__(512, 4) void fused_kernel(
    const float* __restrict__ x, const float* __restrict__ Wx,
    const float* __restrict__ Wt, const float* __restrict__ bh,
    const float* __restrict__ Wa,
    float* __restrict__ vout, float* __restrict__ aout)
{
  __shared__ __attribute__((aligned(16))) _Float16 xbs[4 * XBSUB]; // [jj&3][jj>>2][c]
  __shared__ __attribute__((aligned(16))) _Float16 xc[C_ * XCST];  // [c][jj] (AV B)
  __shared__ __attribute__((aligned(16))) _Float16 a16[16 * XCST]; // [row][jj] (AV A)
  __shared__ __attribute__((aligned(16))) float k2b[96 * KST];     // 0..70 Ek, 80..87 Eq
  __shared__ float vs[C_ * 9];                                     // [c][row]

  const int tid  = threadIdx.x;
  const int lane = tid & 63;
  const int bx   = blockIdx.x;
  const int n    = bx & 7;          // consecutive blocks -> distinct n (XCD-local x)
  const int t    = bx >> 3;
  const int i0   = t << 3;
  const int jbase = i0 - 32;

  const int w   = __builtin_amdgcn_readfirstlane(tid >> 6);   // wave id, uniform
  const int l15 = lane & 15, g = lane >> 4;

  // ---- stage: load cols 0..71 (q<18); zero-fill 72..95; xbs rows 0..79 ----
  #pragma unroll
  for (int it = 0; it < 3; ++it) {
    int idx = tid + it * 512;                // < 1536
    int c = idx / 24, q = idx - c * 24;
    int jj = q << 2;
    float4 xv = {0.f, 0.f, 0.f, 0.f};
    if (q < 18) {
      int j = jbase + jj;                    // j % 4 == 0: quad fully in or out
      if (j >= 0 && j < L_) xv = *(const float4*)(x + (n * C_ + c) * L_ + j);
    }
    f16x4 h = { (_Float16)xv.x, (_Float16)xv.y, (_Float16)xv.z, (_Float16)xv.w };
    *(f16x4*)&xc[c * XCST + jj] = h;         // one b64
    if (q < 20) {                            // rows jj..jj+3 -> subarrays 0..3
      _Float16* p = xbs + q * XB2 + c;       // same (q,c) slot in each subarray
      p[0 * XBSUB] = h[0];
      p[1 * XBSUB] = h[1];
      p[2 * XBSUB] = h[2];
      p[3 * XBSUB] = h[3];
    }
  }
  if (tid < 416) {                           // zero a16 (16*104 f16 / 4)
    f16x4 z = {(_Float16)0.f, (_Float16)0.f, (_Float16)0.f, (_Float16)0.f};
    *(f16x4*)&a16[tid * 4] = z;
  }
  __syncthreads();

  // ---- MFMA proj: wave w -> nt = w&3; store Ek = exp2(acc) ----
  {
    const int nt = w & 3;
    f16x8 bx0, bx1;
    #pragma unroll
    for (int e = 0; e < 8; ++e) {
      bx0[e] = (_Float16)(Wx[(g * 8 + e) * 64 + nt * 16 + l15] * C2F);
      bx1[e] = (_Float16)(Wx[(g * 8 + 32 + e) * 64 + nt * 16 + l15] * C2F);
    }
#define PROJ_UNIT(MT) { \
    const int arow = (MT) * 16 + l15; \
    const _Float16* ap = xbs + (arow & 3) * XBSUB + (arow >> 2) * XB2 + g * 8; \
    f16x8 af0 = *(const f16x8*)ap; \
    f16x8 af1 = *(const f16x8*)(ap + 32); \
    f32x4 acc = {0.f, 0.f, 0.f, 0.f}; \
    acc = __builtin_amdgcn_mfma_f32_16x16x32_f16(af0, bx0, acc, 0, 0, 0); \
    acc = __builtin_amdgcn_mfma_f32_16x16x32_f16(af1, bx1, acc, 0, 0, 0); \
    float* dp = &k2b[((MT) * 16 + g * 4) * KST + nt * 16 + l15]; \
    dp[0] = ex2(acc[0]); dp[KST] = ex2(acc[1]); \
    dp[2 * KST] = ex2(acc[2]); dp[3 * KST] = ex2(acc[3]); }
    if (w < 4) {
      PROJ_UNIT(0)
      PROJ_UNIT(1)
      {  // Q-tile: A = band cols 32..47, B = Wt, bias in acc init; store Eq
        f16x8 bt0, bt1;
        #pragma unroll
        for (int e = 0; e < 8; ++e) {
          bt0[e] = (_Float16)(Wt[(g * 8 + e) * 64 + nt * 16 + l15] * C2F);
          bt1[e] = (_Float16)(Wt[(g * 8 + 32 + e) * 64 + nt * 16 + l15] * C2F);
        }
        const int arow = 32 + l15;
        const _Float16* ap = xbs + (arow & 3) * XBSUB + (arow >> 2) * XB2 + g * 8;
        f16x8 af0 = *(const f16x8*)ap;
        f16x8 af1 = *(const f16x8*)(ap + 32);
        const float b = bh[nt * 16 + l15] * C2F;
        f32x4 qa = {b, b, b, b};
        qa = __builtin_amdgcn_mfma_f32_16x16x32_f16(af0, bt0, qa, 0, 0, 0);
        qa = __builtin_amdgcn_mfma_f32_16x16x32_f16(af1, bt1, qa, 0, 0, 0);
        float* qp = &k2b[(80 + g * 4) * KST + nt * 16 + l15];
        qp[0] = ex2(qa[0]); qp[KST] = ex2(qa[1]);
        qp[2 * KST] = ex2(qa[2]); qp[3 * KST] = ex2(qa[3]);
      }
    } else {
      PROJ_UNIT(2)
      PROJ_UNIT(3)
      PROJ_UNIT(4)   // D rows 64..79; rows 71..79 never read (ex2 junk harmless)
    }
#undef PROJ_UNIT
  }
  __syncthreads();

  // ---- score row i = i0 + w: sigma = rcp(Ek*Eq + 1); Eq via readlane ----
  const int i = i0 + w;
  const float* kp = &k2b[(w + lane) * KST];
  const float eqv = k2b[(80 + w) * KST + lane];   // lane d -> Eq[d], 1 b32/wave
  float a0 = 0.f, a1 = 0.f, a2 = 0.f, a3 = 0.f;
  #pragma unroll
  for (int dc = 0; dc < 64; dc += 4) {
    float4 kv = *(const float4*)(kp + dc);
    float4 wv = *(const float4*)(Wa + dc);        // uniform -> s_load
    const float q0 = rdlane(eqv, dc + 0);         // SGPR broadcasts
    const float q1 = rdlane(eqv, dc + 1);
    const float q2 = rdlane(eqv, dc + 2);
    const float q3 = rdlane(eqv, dc + 3);
    a0 = fmaf(rcp_f(fmaf(kv.x, q0, 1.f)), wv.x, a0);   // sigma(-2x)*Wa_d
    a1 = fmaf(rcp_f(fmaf(kv.y, q1, 1.f)), wv.y, a1);
    a2 = fmaf(rcp_f(fmaf(kv.z, q2, 1.f)), wv.z, a2);
    a3 = fmaf(rcp_f(fmaf(kv.w, q3, 1.f)), wv.w, a3);
  }
  const float acc = (a0 + a1) + (a2 + a3);

  // ---- band softmax (raw = const - 2*acc -> band max == acc min) ----
  const int j = i - 32 + lane;
  const bool valid = (j >= 0) && (j < L_);
  float m = valid ? acc : 1e30f;
  #pragma unroll
  for (int off = 32; off; off >>= 1) m = fminf(m, __shfl_xor(m, off, 64));
  float p = valid ? ex2(C2F * (m - acc)) : 0.f;
  float s = p;
  #pragma unroll
  for (int off = 32; off; off >>= 1) s += __shfl_xor(s, off, 64);
  const float av = p * rcp_f(s + 1e-6f);

  // a16[w][w+lane] = av (f16): row w support = cols w..w+63
  a16[w * XCST + w + lane] = (_Float16)av;

  // coalesced a-row global write: rotate so lane L holds col === L (mod 64)
  {
    const int src  = (lane - i + 32) & 63;
    const float ar = __shfl(av, src, 64);
    const int jsrc = i - 32 + src;            // === lane (mod 64)
    const int seg  = (jsrc >= 0) ? (jsrc >> 6) : 9;
    float* arow = aout + (size_t)(n * L_ + i) * L_;
    #pragma unroll
    for (int s8 = 0; s8 < 8; ++s8)
      arow[s8 * 64 + lane] = (s8 == seg) ? ar : 0.f;
  }
  __syncthreads();

  // ---- AV on matrix pipe: waves 0..3, nt = w; D[row][c] = sum_jj a*x ----
  if (w < 4) {
    const int nt = w;
    f32x4 vacc = {0.f, 0.f, 0.f, 0.f};
    #pragma unroll
    for (int kk = 0; kk < 3; ++kk) {          // K = jj 0..95 (zero-padded)
      f16x8 af = *(const f16x8*)&a16[l15 * XCST + kk * 32 + g * 8];
      f16x8 bf = *(const f16x8*)&xc[(nt * 16 + l15) * XCST + kk * 32 + g * 8];
      vacc = __builtin_amdgcn_mfma_f32_16x16x32_f16(af, bf, vacc, 0, 0, 0);
    }
    if (g < 2) {                              // rows 0..7 valid
      float* vp = &vs[(nt * 16 + l15) * 9 + g * 4];
      vp[0] = vacc[0]; vp[1] = vacc[1]; vp[2] = vacc[2]; vp[3] = vacc[3];
    }
  }
  __syncthreads();
  {
    int c = tid >> 3, il = tid & 7;
    vout[((size_t)n * C_ + c) * L_ + i0 + il] = vs[c * 9 + il];
  }
}

extern "C" void kernel_launch(void* const* d_in, const int* in_sizes, int n_in,
                              void* d_out, int out_size, void* d_ws, size_t ws_size,
                              hipStream_t stream) {
  const float* x  = (const float*)d_in[0];
  const float* Wx = (const float*)d_in[1];   // key proj
  const float* Wt = (const float*)d_in[2];   // query proj
  const float* bh = (const float*)d_in[3];
  const float* Wa = (const float*)d_in[4];
  // d_in[5] (ba) cancels in the softmax: unused.
  (void)d_ws; (void)ws_size;

  float* vout = (float*)d_out;               // N*C*L
  float* aout = vout + N_ * C_ * L_;         // N*L*L

  fused_kernel<<<512, 512, 0, stream>>>(x, Wx, Wt, bh, Wa, vout, aout);
}

// Round 17
// 12.229 us; speedup vs baseline: 1.0344x; 1.0344x over previous
//
#include <hip/hip_runtime.h>

#define N_ 8
#define C_ 64
#define L_ 512
#define KST 68        // k2b row stride (dwords): ==4 mod 32 -> uniform-8 b128 (floor)
#define XCST 104      // xc/a16 row stride (f16): 52 dwords ==20 mod 32 -> 2-way b128
#define XB2 72        // xbs inner row stride (f16): 144B, 16B-multiple
#define XBSUB (20 * XB2)  // one jj-mod-4 subarray: 20 rows

#define C2F 2.8853900817779268f   // 2*log2(e)

typedef _Float16 f16x8 __attribute__((ext_vector_type(8)));
typedef _Float16 f16x4 __attribute__((ext_vector_type(4)));
typedef float    f32x4 __attribute__((ext_vector_type(4)));

__device__ __forceinline__ float rcp_f(float x) { return __builtin_amdgcn_rcpf(x); }
__device__ __forceinline__ float ex2(float x)   { return __builtin_amdgcn_exp2f(x); }

// Single fused kernel; proj AND AV on the matrix pipe.  (R15 structure — best.)
// k2b stores E = exp2(C2F * proj): sigma = rcp(fma(Ek, Eq, 1)) -> no exp in loop.
// xc cols 72..95 zero-filled (a16 support ends at col 70 -> exact no-op).
// grid 512 = (n = bx&7 -> XCD-local batch, t = bx>>3), 512 thr = 8 waves.
__global__ __launch_bounds__(512, 4) void fused_kernel(
    const float* __restrict__ x, const float* __restrict__ Wx,
    const float* __restrict__ Wt, const float* __restrict__ bh,
    const float* __restrict__ Wa,
    float* __restrict__ vout, float* __restrict__ aout)
{
  __shared__ __attribute__((aligned(16))) _Float16 xbs[4 * XBSUB]; // [jj&3][jj>>2][c]
  __shared__ __attribute__((aligned(16))) _Float16 xc[C_ * XCST];  // [c][jj] (AV B)
  __shared__ __attribute__((aligned(16))) _Float16 a16[16 * XCST]; // [row][jj] (AV A)
  __shared__ __attribute__((aligned(16))) float k2b[96 * KST];     // 0..70 Ek, 80..87 Eq
  __shared__ float vs[C_ * 9];                                     // [c][row]

  const int tid  = threadIdx.x;
  const int lane = tid & 63;
  const int bx   = blockIdx.x;
  const int n    = bx & 7;          // consecutive blocks -> distinct n (XCD-local x)
  const int t    = bx >> 3;
  const int i0   = t << 3;
  const int jbase = i0 - 32;

  const int w   = __builtin_amdgcn_readfirstlane(tid >> 6);   // wave id, uniform
  const int l15 = lane & 15, g = lane >> 4;

  // ---- stage: load cols 0..71 (q<18); zero-fill 72..95; xbs rows 0..79 ----
  #pragma unroll
  for (int it = 0; it < 3; ++it) {
    int idx = tid + it * 512;                // < 1536
    int c = idx / 24, q = idx - c * 24;
    int jj = q << 2;
    float4 xv = {0.f, 0.f, 0.f, 0.f};
    if (q < 18) {
      int j = jbase + jj;                    // j % 4 == 0: quad fully in or out
      if (j >= 0 && j < L_) xv = *(const float4*)(x + (n * C_ + c) * L_ + j);
    }
    f16x4 h = { (_Float16)xv.x, (_Float16)xv.y, (_Float16)xv.z, (_Float16)xv.w };
    *(f16x4*)&xc[c * XCST + jj] = h;         // one b64
    if (q < 20) {                            // rows jj..jj+3 -> subarrays 0..3
      _Float16* p = xbs + q * XB2 + c;       // same (q,c) slot in each subarray
      p[0 * XBSUB] = h[0];
      p[1 * XBSUB] = h[1];
      p[2 * XBSUB] = h[2];
      p[3 * XBSUB] = h[3];
    }
  }
  if (tid < 416) {                           // zero a16 (16*104 f16 / 4)
    f16x4 z = {(_Float16)0.f, (_Float16)0.f, (_Float16)0.f, (_Float16)0.f};
    *(f16x4*)&a16[tid * 4] = z;
  }
  __syncthreads();

  // ---- MFMA proj: wave w -> nt = w&3; store Ek = exp2(acc) ----
  {
    const int nt = w & 3;
    f16x8 bx0, bx1;
    #pragma unroll
    for (int e = 0; e < 8; ++e) {
      bx0[e] = (_Float16)(Wx[(g * 8 + e) * 64 + nt * 16 + l15] * C2F);
      bx1[e] = (_Float16)(Wx[(g * 8 + 32 + e) * 64 + nt * 16 + l15] * C2F);
    }
#define PROJ_UNIT(MT) { \
    const int arow = (MT) * 16 + l15; \
    const _Float16* ap = xbs + (arow & 3) * XBSUB + (arow >> 2) * XB2 + g * 8; \
    f16x8 af0 = *(const f16x8*)ap; \
    f16x8 af1 = *(const f16x8*)(ap + 32); \
    f32x4 acc = {0.f, 0.f, 0.f, 0.f}; \
    acc = __builtin_amdgcn_mfma_f32_16x16x32_f16(af0, bx0, acc, 0, 0, 0); \
    acc = __builtin_amdgcn_mfma_f32_16x16x32_f16(af1, bx1, acc, 0, 0, 0); \
    float* dp = &k2b[((MT) * 16 + g * 4) * KST + nt * 16 + l15]; \
    dp[0] = ex2(acc[0]); dp[KST] = ex2(acc[1]); \
    dp[2 * KST] = ex2(acc[2]); dp[3 * KST] = ex2(acc[3]); }
    if (w < 4) {
      PROJ_UNIT(0)
      PROJ_UNIT(1)
      {  // Q-tile: A = band cols 32..47, B = Wt, bias in acc init; store Eq
        f16x8 bt0, bt1;
        #pragma unroll
        for (int e = 0; e < 8; ++e) {
          bt0[e] = (_Float16)(Wt[(g * 8 + e) * 64 + nt * 16 + l15] * C2F);
          bt1[e] = (_Float16)(Wt[(g * 8 + 32 + e) * 64 + nt * 16 + l15] * C2F);
        }
        const int arow = 32 + l15;
        const _Float16* ap = xbs + (arow & 3) * XBSUB + (arow >> 2) * XB2 + g * 8;
        f16x8 af0 = *(const f16x8*)ap;
        f16x8 af1 = *(const f16x8*)(ap + 32);
        const float b = bh[nt * 16 + l15] * C2F;
        f32x4 qa = {b, b, b, b};
        qa = __builtin_amdgcn_mfma_f32_16x16x32_f16(af0, bt0, qa, 0, 0, 0);
        qa = __builtin_amdgcn_mfma_f32_16x16x32_f16(af1, bt1, qa, 0, 0, 0);
        float* qp = &k2b[(80 + g * 4) * KST + nt * 16 + l15];
        qp[0] = ex2(qa[0]); qp[KST] = ex2(qa[1]);
        qp[2 * KST] = ex2(qa[2]); qp[3 * KST] = ex2(qa[3]);
      }
    } else {
      PROJ_UNIT(2)
      PROJ_UNIT(3)
      PROJ_UNIT(4)   // D rows 64..79; rows 71..79 never read (ex2 junk harmless)
    }
#undef PROJ_UNIT
  }
  __syncthreads();

  // ---- score row i = i0 + w: sigma = rcp(Ek*Eq + 1), no exp in loop ----
  const int i = i0 + w;
  const float* kp = &k2b[(w + lane) * KST];
  const float* qp = &k2b[(80 + w) * KST];   // uniform -> broadcast b128
  float a0 = 0.f, a1 = 0.f, a2 = 0.f, a3 = 0.f;
  #pragma unroll 4
  for (int dc = 0; dc < 64; dc += 4) {
    float4 kv = *(const float4*)(kp + dc);
    float4 qv = *(const float4*)(qp + dc);
    float4 wv = *(const float4*)(Wa + dc);  // uniform -> s_load
    a0 = fmaf(rcp_f(fmaf(kv.x, qv.x, 1.f)), wv.x, a0);   // sigma(-2x)*Wa_d
    a1 = fmaf(rcp_f(fmaf(kv.y, qv.y, 1.f)), wv.y, a1);
    a2 = fmaf(rcp_f(fmaf(kv.z, qv.z, 1.f)), wv.z, a2);
    a3 = fmaf(rcp_f(fmaf(kv.w, qv.w, 1.f)), wv.w, a3);
  }
  const float acc = (a0 + a1) + (a2 + a3);

  // ---- band softmax (raw = const - 2*acc -> band max == acc min) ----
  const int j = i - 32 + lane;
  const bool valid = (j >= 0) && (j < L_);
  float m = valid ? acc : 1e30f;
  #pragma unroll
  for (int off = 32; off; off >>= 1) m = fminf(m, __shfl_xor(m, off, 64));
  float p = valid ? ex2(C2F * (m - acc)) : 0.f;
  float s = p;
  #pragma unroll
  for (int off = 32; off; off >>= 1) s += __shfl_xor(s, off, 64);
  const float av = p * rcp_f(s + 1e-6f);

  // a16[w][w+lane] = av (f16): row w support = cols w..w+63
  a16[w * XCST + w + lane] = (_Float16)av;

  // coalesced a-row global write: rotate so lane L holds col === L (mod 64)
  {
    const int src  = (lane - i + 32) & 63;
    const float ar = __shfl(av, src, 64);
    const int jsrc = i - 32 + src;            // === lane (mod 64)
    const int seg  = (jsrc >= 0) ? (jsrc >> 6) : 9;
    float* arow = aout + (size_t)(n * L_ + i) * L_;
    #pragma unroll
    for (int s8 = 0; s8 < 8; ++s8)
      arow[s8 * 64 + lane] = (s8 == seg) ? ar : 0.f;
  }
  __syncthreads();

  // ---- AV on matrix pipe: waves 0..3, nt = w; D[row][c] = sum_jj a*x ----
  if (w < 4) {
    const int nt = w;
    f32x4 vacc = {0.f, 0.f, 0.f, 0.f};
    #pragma unroll
    for (int kk = 0; kk < 3; ++kk) {          // K = jj 0..95 (zero-padded)
      f16x8 af = *(const f16x8*)&a16[l15 * XCST + kk * 32 + g * 8];
      f16x8 bf = *(const f16x8*)&xc[(nt * 16 + l15) * XCST + kk * 32 + g * 8];
      vacc = __builtin_amdgcn_mfma_f32_16x16x32_f16(af, bf, vacc, 0, 0, 0);
    }
    if (g < 2) {                              // rows 0..7 valid
      float* vp = &vs[(nt * 16 + l15) * 9 + g * 4];
      vp[0] = vacc[0]; vp[1] = vacc[1]; vp[2] = vacc[2]; vp[3] = vacc[3];
    }
  }
  __syncthreads();
  {
    int c = tid >> 3, il = tid & 7;
    vout[((size_t)n * C_ + c) * L_ + i0 + il] = vs[c * 9 + il];
  }
}

extern "C" void kernel_launch(void* const* d_in, const int* in_sizes, int n_in,
                              void* d_out, int out_size, void* d_ws, size_t ws_size,
                              hipStream_t stream) {
  const float* x  = (const float*)d_in[0];
  const float* Wx = (const float*)d_in[1];   // key proj
  const float* Wt = (const float*)d_in[2];   // query proj
  const float* bh = (const float*)d_in[3];
  const float* Wa = (const float*)d_in[4];
  // d_in[5] (ba) cancels in the softmax: unused.
  (void)d_ws; (void)ws_size;

  float* vout = (float*)d_out;               // N*C*L
  float* aout = vout + N_ * C_ * L_;         // N*L*L

  fused_kernel<<<512, 512, 0, stream>>>(x, Wx, Wt, bh, Wa, vout, aout);
}